// Round 6
// baseline (465.104 us; speedup 1.0000x reference)
//
#include <hip/hip_runtime.h>
#include <hip/hip_bf16.h>
#include <float.h>
#include <math.h>

// Problem constants (from reference)
#define NN 20000
#define EE 320000
#define IN_DIM 128
#define SLOPE_ 0.2f

typedef __attribute__((ext_vector_type(8))) short bf16x8;
typedef __attribute__((ext_vector_type(4))) float f32x4;
typedef unsigned short ushort;

// ---------- bf16 helpers ----------
__device__ inline ushort f32_to_bf16_rn(float f) {
    unsigned u = __float_as_uint(f);
    unsigned rounding = 0x7FFFu + ((u >> 16) & 1u);
    return (ushort)((u + rounding) >> 16);
}
__device__ inline float bf16u_to_f32(ushort h) {
    return __uint_as_float(((unsigned)h) << 16);
}

// ---------- split fp32 -> (hi, lo) bf16 (used only for input x) ----------
__global__ void split_f32(const float* __restrict__ A, ushort* __restrict__ hi,
                          ushort* __restrict__ lo, int n4) {
    int i = blockIdx.x * blockDim.x + threadIdx.x;
    if (i >= n4) return;
    float4 v = ((const float4*)A)[i];
    ushort h0 = f32_to_bf16_rn(v.x), h1 = f32_to_bf16_rn(v.y);
    ushort h2 = f32_to_bf16_rn(v.z), h3 = f32_to_bf16_rn(v.w);
    ushort l0 = f32_to_bf16_rn(v.x - bf16u_to_f32(h0));
    ushort l1 = f32_to_bf16_rn(v.y - bf16u_to_f32(h1));
    ushort l2 = f32_to_bf16_rn(v.z - bf16u_to_f32(h2));
    ushort l3 = f32_to_bf16_rn(v.w - bf16u_to_f32(h3));
    ((ushort4*)hi)[i] = make_ushort4(h0, h1, h2, h3);
    ((ushort4*)lo)[i] = make_ushort4(l0, l1, l2, l3);
}

// ---------- weight prep: concat + transpose + split, plus bias concat ----------
__global__ void prep_w(const float* __restrict__ Wa, const float* __restrict__ ba, int na,
                       const float* __restrict__ Wb, const float* __restrict__ bb, int nb,
                       const float* __restrict__ Wc, const float* __restrict__ bc, int nc,
                       int K, ushort* __restrict__ Wt_hi, ushort* __restrict__ Wt_lo,
                       float* __restrict__ bias_cat) {
    int idx = blockIdx.x * blockDim.x + threadIdx.x;
    int S = na + nb + nc;
    if (idx >= S * K) return;
    int n = idx / K;
    int k = idx - n * K;
    const float* W; const float* b; int nl; int ncols;
    if (n < na) { W = Wa; b = ba; nl = n; ncols = na; }
    else if (n < na + nb) { W = Wb; b = bb; nl = n - na; ncols = nb; }
    else { W = Wc; b = bc; nl = n - na - nb; ncols = nc; }
    float v = W[(size_t)k * ncols + nl];
    ushort h = f32_to_bf16_rn(v);
    ushort l = f32_to_bf16_rn(v - bf16u_to_f32(h));
    Wt_hi[(size_t)n * K + k] = h;
    Wt_lo[(size_t)n * K + k] = l;
    if (k == 0) bias_cat[n] = b[nl];
}

// ---------- split-bf16 MFMA GEMM: C[M][S] = A[M][K] @ Wt^T + bias ----------
// BM=256 (4 waves x 64 rows, mt=4), BN=64, BK=32.
#define BSTRIDE 40
__global__ __launch_bounds__(256) void gemm_mfma_split(
        const ushort* __restrict__ Ahi, const ushort* __restrict__ Alo,
        const ushort* __restrict__ Wth, const ushort* __restrict__ Wtl,
        const float* __restrict__ bias, float* __restrict__ C,
        int M, int K, int S) {
    __shared__ ushort Bs_hi[64 * BSTRIDE];
    __shared__ ushort Bs_lo[64 * BSTRIDE];
    const int bm = blockIdx.y * 256;
    const int bn = blockIdx.x * 64;
    const int tid = threadIdx.x;
    const int wave = tid >> 6;
    const int lane = tid & 63;
    const int m16 = lane & 15;
    const int quad = lane >> 4;

    f32x4 acc[4][4];
    #pragma unroll
    for (int i = 0; i < 4; ++i)
        #pragma unroll
        for (int j = 0; j < 4; ++j) acc[i][j] = (f32x4){0.f, 0.f, 0.f, 0.f};

    const int srow = tid >> 2;
    const int schk = tid & 3;

    for (int k0 = 0; k0 < K; k0 += 32) {
        // --- stage B tile (64 x 32, hi+lo) ---
        {
            size_t goff = (size_t)(bn + srow) * K + k0 + schk * 8;
            bf16x8 vh = *(const bf16x8*)(Wth + goff);
            bf16x8 vl = *(const bf16x8*)(Wtl + goff);
            *(bf16x8*)&Bs_hi[srow * BSTRIDE + schk * 8] = vh;
            *(bf16x8*)&Bs_lo[srow * BSTRIDE + schk * 8] = vl;
        }
        // --- A fragments direct from global (4 m-tiles per wave) ---
        bf16x8 ah[4], al[4];
        #pragma unroll
        for (int mt = 0; mt < 4; ++mt) {
            int row = bm + wave * 64 + mt * 16 + m16;
            row = row < M ? row : M - 1;
            size_t goff = (size_t)row * K + k0 + quad * 8;
            ah[mt] = *(const bf16x8*)(Ahi + goff);
            al[mt] = *(const bf16x8*)(Alo + goff);
        }
        __syncthreads();
        #pragma unroll
        for (int nt = 0; nt < 4; ++nt) {
            int boff = (nt * 16 + m16) * BSTRIDE + quad * 8;
            bf16x8 bh = *(const bf16x8*)&Bs_hi[boff];
            bf16x8 bl = *(const bf16x8*)&Bs_lo[boff];
            #pragma unroll
            for (int mt = 0; mt < 4; ++mt) {
                acc[mt][nt] = __builtin_amdgcn_mfma_f32_16x16x32_bf16(ah[mt], bh, acc[mt][nt], 0, 0, 0);
                acc[mt][nt] = __builtin_amdgcn_mfma_f32_16x16x32_bf16(ah[mt], bl, acc[mt][nt], 0, 0, 0);
                acc[mt][nt] = __builtin_amdgcn_mfma_f32_16x16x32_bf16(al[mt], bh, acc[mt][nt], 0, 0, 0);
            }
        }
        __syncthreads();
    }

    #pragma unroll
    for (int nt = 0; nt < 4; ++nt) {
        int col = bn + nt * 16 + m16;
        float bv = bias[col];
        #pragma unroll
        for (int mt = 0; mt < 4; ++mt) {
            #pragma unroll
            for (int r = 0; r < 4; ++r) {
                int row = bm + wave * 64 + mt * 16 + quad * 4 + r;
                if (row < M) C[(size_t)row * S + col] = acc[mt][nt][r] + bv;
            }
        }
    }
}

// ---------- CSR build ----------
__global__ void zero_u32(unsigned int* __restrict__ p, int n) {
    int i = blockIdx.x * blockDim.x + threadIdx.x;
    if (i < n) p[i] = 0u;
}

__global__ void hist_dst(const int* __restrict__ dst, unsigned int* __restrict__ deg, int E) {
    int e = blockIdx.x * blockDim.x + threadIdx.x;
    if (e < E) atomicAdd(&deg[dst[e]], 1u);
}

__global__ void scan_deg(const unsigned int* __restrict__ deg,
                         unsigned int* __restrict__ row_ptr,
                         unsigned int* __restrict__ cursor, int n) {
    __shared__ unsigned int sums[1024];
    const int t = threadIdx.x;
    const int chunk = (n + 1023) / 1024;
    const int start = t * chunk;
    const int end = min(start + chunk, n);
    unsigned int s = 0;
    for (int i = start; i < end; ++i) s += deg[i];
    sums[t] = s;
    __syncthreads();
    for (int off = 1; off < 1024; off <<= 1) {
        unsigned int v = (t >= off) ? sums[t - off] : 0u;
        __syncthreads();
        sums[t] += v;
        __syncthreads();
    }
    unsigned int prefix = (t == 0) ? 0u : sums[t - 1];
    for (int i = start; i < end; ++i) {
        row_ptr[i] = prefix;
        cursor[i] = prefix;
        prefix += deg[i];
    }
    if (t == 1023) row_ptr[n] = sums[1023];
}

__global__ void scatter_edges(const int* __restrict__ src, const int* __restrict__ dst,
                              unsigned int* __restrict__ cursor,
                              int* __restrict__ csr_src, int E) {
    int e = blockIdx.x * blockDim.x + threadIdx.x;
    if (e < E) {
        unsigned int pos = atomicAdd(&cursor[dst[e]], 1u);
        csr_src[pos] = src[e];
    }
}

// ---------- fused GATv2 aggregate: one wave per node, float4 lanes, 2-way edge ILP ----------
// Lane i owns dims 4i..4i+3 (one head: 4 | D). Butterfly over D/4 lanes.
// OUT_MODE: 0 = fp32 out + bf16 hi/lo; 1 = bf16 hi/lo only; 2 = head-mean -> out[N,32].
template <int HD, int D, bool HAS_RES, bool DO_ELU, int OUT_MODE>
__global__ __launch_bounds__(256) void gat_node_aggregate(
        const float* __restrict__ feat, int FS,
        const float* __restrict__ attn,
        const unsigned int* __restrict__ row_ptr,
        const int* __restrict__ csr_src,
        const float* __restrict__ resid, int RS,
        float* __restrict__ outF, ushort* __restrict__ outH, ushort* __restrict__ outL) {
    constexpr int LANES = HD / 4;   // active lanes per node (64 or 48)
    constexpr int GSZ = D / 4;      // lanes per head group (16 or 8)
    __shared__ float red[4][(OUT_MODE == 2) ? HD : 1];

    const int wave = threadIdx.x >> 6;
    const int lane = threadIdx.x & 63;
    const int t = blockIdx.x * 4 + wave;
    const bool active = (lane < LANES);
    const int off = active ? 4 * lane : 0;

    float4 fdv = make_float4(0.f, 0.f, 0.f, 0.f);
    float4 a6 = fdv, a4 = fdv;
    if (active) {
        fdv = *(const float4*)&feat[(size_t)t * FS + HD + off];
        float4 a = *(const float4*)&attn[off];
        a6 = make_float4(0.6f * a.x, 0.6f * a.y, 0.6f * a.z, 0.6f * a.w);
        a4 = make_float4(0.4f * a.x, 0.4f * a.y, 0.4f * a.z, 0.4f * a.w);
    }

    const unsigned int j0 = row_ptr[t], j1 = row_ptr[t + 1];

    // two independent online-softmax streams (even/odd edges)
    float4 acc0 = make_float4(0.f, 0.f, 0.f, 0.f), acc1 = acc0;
    float lh0 = 0.f, lh1 = 0.f, mh0 = -INFINITY, mh1 = -INFINITY;

    float4 c0 = acc0, c1 = acc0;
    if (active && j0 < j1) c0 = *(const float4*)&feat[(size_t)csr_src[j0] * FS + off];
    if (active && j0 + 1 < j1) c1 = *(const float4*)&feat[(size_t)csr_src[j0 + 1] * FS + off];

    for (unsigned int j = j0; j < j1; j += 2) {
        float4 n0 = make_float4(0.f, 0.f, 0.f, 0.f), n1 = n0;
        if (active && j + 2 < j1) n0 = *(const float4*)&feat[(size_t)csr_src[j + 2] * FS + off];
        if (active && j + 3 < j1) n1 = *(const float4*)&feat[(size_t)csr_src[j + 3] * FS + off];

        // ---- stream 0 (edge j, always valid) ----
        {
            float x0 = c0.x + fdv.x, x1 = c0.y + fdv.y;
            float x2 = c0.z + fdv.z, x3 = c0.w + fdv.w;
            float p = x0 * a6.x + fabsf(x0) * a4.x;
            p += x1 * a6.y + fabsf(x1) * a4.y;
            p += x2 * a6.z + fabsf(x2) * a4.z;
            p += x3 * a6.w + fabsf(x3) * a4.w;
            #pragma unroll
            for (int o = 1; o < GSZ; o <<= 1)
                p += __shfl_xor(p, o, 64);
            float nm = fmaxf(mh0, p);
            float sc = __expf(mh0 - nm);
            float w = __expf(p - nm);
            lh0 = lh0 * sc + w;
            acc0.x = acc0.x * sc + w * c0.x;
            acc0.y = acc0.y * sc + w * c0.y;
            acc0.z = acc0.z * sc + w * c0.z;
            acc0.w = acc0.w * sc + w * c0.w;
            mh0 = nm;
        }
        // ---- stream 1 (edge j+1, predicated; wave-uniform branch) ----
        if (j + 1 < j1) {
            float x0 = c1.x + fdv.x, x1 = c1.y + fdv.y;
            float x2 = c1.z + fdv.z, x3 = c1.w + fdv.w;
            float p = x0 * a6.x + fabsf(x0) * a4.x;
            p += x1 * a6.y + fabsf(x1) * a4.y;
            p += x2 * a6.z + fabsf(x2) * a4.z;
            p += x3 * a6.w + fabsf(x3) * a4.w;
            #pragma unroll
            for (int o = 1; o < GSZ; o <<= 1)
                p += __shfl_xor(p, o, 64);
            float nm = fmaxf(mh1, p);
            float sc = __expf(mh1 - nm);
            float w = __expf(p - nm);
            lh1 = lh1 * sc + w;
            acc1.x = acc1.x * sc + w * c1.x;
            acc1.y = acc1.y * sc + w * c1.y;
            acc1.z = acc1.z * sc + w * c1.z;
            acc1.w = acc1.w * sc + w * c1.w;
            mh1 = nm;
        }
        c0 = n0;
        c1 = n1;
    }

    // merge streams (deg>=1 => mh0 finite => no NaN; exp(-inf - finite) = 0)
    float4 vout = make_float4(0.f, 0.f, 0.f, 0.f);
    if (j0 < j1) {
        float m = fmaxf(mh0, mh1);
        float s0 = __expf(mh0 - m);
        float s1 = __expf(mh1 - m);
        float lh = lh0 * s0 + lh1 * s1;
        float inv = 1.f / lh;
        vout.x = (acc0.x * s0 + acc1.x * s1) * inv;
        vout.y = (acc0.y * s0 + acc1.y * s1) * inv;
        vout.z = (acc0.z * s0 + acc1.z * s1) * inv;
        vout.w = (acc0.w * s0 + acc1.w * s1) * inv;
    }

    if (HAS_RES && active) {
        float4 r = *(const float4*)&resid[(size_t)t * RS + off];
        vout.x += r.x; vout.y += r.y; vout.z += r.z; vout.w += r.w;
    }
    if (DO_ELU) {
        vout.x = vout.x > 0.f ? vout.x : expm1f(vout.x);
        vout.y = vout.y > 0.f ? vout.y : expm1f(vout.y);
        vout.z = vout.z > 0.f ? vout.z : expm1f(vout.z);
        vout.w = vout.w > 0.f ? vout.w : expm1f(vout.w);
    }

    if (OUT_MODE == 2) {
        if (active) *(float4*)&red[wave][off] = vout;
        __syncthreads();
        if (lane < 32) {
            float ssum = 0.f;
            #pragma unroll
            for (int h = 0; h < 6; ++h) ssum += red[wave][h * 32 + lane];
            outF[(size_t)t * 32 + lane] = ssum * (1.f / 6.f);
        }
    } else if (active) {
        ushort4 hv = make_ushort4(f32_to_bf16_rn(vout.x), f32_to_bf16_rn(vout.y),
                                  f32_to_bf16_rn(vout.z), f32_to_bf16_rn(vout.w));
        ushort4 lv = make_ushort4(f32_to_bf16_rn(vout.x - bf16u_to_f32(hv.x)),
                                  f32_to_bf16_rn(vout.y - bf16u_to_f32(hv.y)),
                                  f32_to_bf16_rn(vout.z - bf16u_to_f32(hv.z)),
                                  f32_to_bf16_rn(vout.w - bf16u_to_f32(hv.w)));
        *(ushort4*)&outH[(size_t)t * HD + off] = hv;
        *(ushort4*)&outL[(size_t)t * HD + off] = lv;
        if (OUT_MODE == 0) *(float4*)&outF[(size_t)t * HD + off] = vout;
    }
}

extern "C" void kernel_launch(void* const* d_in, const int* in_sizes, int n_in,
                              void* d_out, int out_size, void* d_ws, size_t ws_size,
                              hipStream_t stream) {
    const float* x   = (const float*)d_in[0];
    const int*   src = (const int*)d_in[1];
    const int*   dst = (const int*)d_in[2];
    const float* W0s = (const float*)d_in[3];
    const float* b0s = (const float*)d_in[4];
    const float* W0d = (const float*)d_in[5];
    const float* b0d = (const float*)d_in[6];
    const float* a0  = (const float*)d_in[7];
    const float* W1s = (const float*)d_in[8];
    const float* b1s = (const float*)d_in[9];
    const float* W1d = (const float*)d_in[10];
    const float* b1d = (const float*)d_in[11];
    const float* a1  = (const float*)d_in[12];
    const float* W2s = (const float*)d_in[13];
    const float* b2s = (const float*)d_in[14];
    const float* W2d = (const float*)d_in[15];
    const float* b2d = (const float*)d_in[16];
    const float* a2  = (const float*)d_in[17];
    const float* Wr2 = (const float*)d_in[18];
    const float* br2 = (const float*)d_in[19];

    // ---- workspace layout ----
    float* fsd = (float*)d_ws;                       // N*576 fp32 (max layer width)
    float* O0  = fsd + (size_t)NN * 576;             // N*256 (L0 out fp32 = L1 residual)
    ushort* Ah = (ushort*)(O0 + (size_t)NN * 256);   // N*256 bf16
    ushort* Al = Ah + (size_t)NN * 256;              // N*256
    ushort* Wt0h = Al + (size_t)NN * 256;            // 512*128
    ushort* Wt0l = Wt0h + 512 * 128;
    ushort* Wt1h = Wt0l + 512 * 128;                 // 512*256
    ushort* Wt1l = Wt1h + 512 * 256;
    ushort* Wt2h = Wt1l + 512 * 256;                 // 576*256
    ushort* Wt2l = Wt2h + 576 * 256;
    float* bias0 = (float*)(Wt2l + 576 * 256);       // 512
    float* bias1 = bias0 + 512;                      // 512
    float* bias2 = bias1 + 512;                      // 576
    unsigned int* row_ptr = (unsigned int*)(bias2 + 576);  // N+1
    unsigned int* cursor  = row_ptr + (NN + 1);
    unsigned int* deg     = cursor + NN;
    int* csr_src          = (int*)(deg + NN);        // E

    // ---- build CSR ----
    zero_u32<<<(NN + 255) / 256, 256, 0, stream>>>(deg, NN);
    hist_dst<<<(EE + 255) / 256, 256, 0, stream>>>(dst, deg, EE);
    scan_deg<<<1, 1024, 0, stream>>>(deg, row_ptr, cursor, NN);
    scatter_edges<<<(EE + 255) / 256, 256, 0, stream>>>(src, dst, cursor, csr_src, EE);

    // ---- prep all weights ----
    prep_w<<<(512 * 128 + 255) / 256, 256, 0, stream>>>(
        W0s, b0s, 256, W0d, b0d, 256, nullptr, nullptr, 0, 128, Wt0h, Wt0l, bias0);
    prep_w<<<(512 * 256 + 255) / 256, 256, 0, stream>>>(
        W1s, b1s, 256, W1d, b1d, 256, nullptr, nullptr, 0, 256, Wt1h, Wt1l, bias1);
    prep_w<<<(576 * 256 + 255) / 256, 256, 0, stream>>>(
        W2s, b2s, 192, W2d, b2d, 192, Wr2, br2, 192, 256, Wt2h, Wt2l, bias2);

    const int gy = (NN + 255) / 256;  // 79 (BM=256)
    const int nagg = NN / 4;          // 5000 blocks, 4 nodes (waves) each

    // ---- layer 0: x[N,128] -> fsd[N,512] -> O0 fp32 + Ah/Al bf16 ----
    split_f32<<<((NN * 128 / 4) + 255) / 256, 256, 0, stream>>>(x, Ah, Al, NN * 128 / 4);
    gemm_mfma_split<<<dim3(8, gy), 256, 0, stream>>>(Ah, Al, Wt0h, Wt0l, bias0, fsd,
                                                     NN, 128, 512);
    gat_node_aggregate<256, 64, false, true, 0><<<nagg, 256, 0, stream>>>(
        fsd, 512, a0, row_ptr, csr_src, nullptr, 0, O0, Ah, Al);

    // ---- layer 1: Ah/Al -> fsd[N,512] -> Ah/Al (identity residual O0) ----
    gemm_mfma_split<<<dim3(8, gy), 256, 0, stream>>>(Ah, Al, Wt1h, Wt1l, bias1, fsd,
                                                     NN, 256, 512);
    gat_node_aggregate<256, 64, true, true, 1><<<nagg, 256, 0, stream>>>(
        fsd, 512, a1, row_ptr, csr_src, O0, 256, nullptr, Ah, Al);

    // ---- layer 2: Ah/Al -> fsd[N,576] (fs|fd|res) -> d_out[N,32] ----
    gemm_mfma_split<<<dim3(9, gy), 256, 0, stream>>>(Ah, Al, Wt2h, Wt2l, bias2, fsd,
                                                     NN, 256, 576);
    gat_node_aggregate<192, 32, true, false, 2><<<nagg, 256, 0, stream>>>(
        fsd, 576, a2, row_ptr, csr_src, fsd + 384, 576, (float*)d_out, nullptr, nullptr);
}

// Round 7
// 448.862 us; speedup vs baseline: 1.0362x; 1.0362x over previous
//
#include <hip/hip_runtime.h>
#include <hip/hip_bf16.h>
#include <float.h>
#include <math.h>

// Problem constants (from reference)
#define NN 20000
#define EE 320000
#define IN_DIM 128
#define SLOPE_ 0.2f

typedef __attribute__((ext_vector_type(8))) short bf16x8;
typedef __attribute__((ext_vector_type(4))) float f32x4;
typedef unsigned short ushort;

// ---------- bf16 helpers ----------
__device__ inline ushort f32_to_bf16_rn(float f) {
    unsigned u = __float_as_uint(f);
    unsigned rounding = 0x7FFFu + ((u >> 16) & 1u);
    return (ushort)((u + rounding) >> 16);
}
__device__ inline float bf16u_to_f32(ushort h) {
    return __uint_as_float(((unsigned)h) << 16);
}

// ---------- split fp32 -> (hi, lo) bf16 (used only for input x) ----------
__global__ void split_f32(const float* __restrict__ A, ushort* __restrict__ hi,
                          ushort* __restrict__ lo, int n4) {
    int i = blockIdx.x * blockDim.x + threadIdx.x;
    if (i >= n4) return;
    float4 v = ((const float4*)A)[i];
    ushort h0 = f32_to_bf16_rn(v.x), h1 = f32_to_bf16_rn(v.y);
    ushort h2 = f32_to_bf16_rn(v.z), h3 = f32_to_bf16_rn(v.w);
    ushort l0 = f32_to_bf16_rn(v.x - bf16u_to_f32(h0));
    ushort l1 = f32_to_bf16_rn(v.y - bf16u_to_f32(h1));
    ushort l2 = f32_to_bf16_rn(v.z - bf16u_to_f32(h2));
    ushort l3 = f32_to_bf16_rn(v.w - bf16u_to_f32(h3));
    ((ushort4*)hi)[i] = make_ushort4(h0, h1, h2, h3);
    ((ushort4*)lo)[i] = make_ushort4(l0, l1, l2, l3);
}

// ---------- weight prep: concat + transpose + split, plus bias concat ----------
__global__ void prep_w(const float* __restrict__ Wa, const float* __restrict__ ba, int na,
                       const float* __restrict__ Wb, const float* __restrict__ bb, int nb,
                       const float* __restrict__ Wc, const float* __restrict__ bc, int nc,
                       int K, ushort* __restrict__ Wt_hi, ushort* __restrict__ Wt_lo,
                       float* __restrict__ bias_cat) {
    int idx = blockIdx.x * blockDim.x + threadIdx.x;
    int S = na + nb + nc;
    if (idx >= S * K) return;
    int n = idx / K;
    int k = idx - n * K;
    const float* W; const float* b; int nl; int ncols;
    if (n < na) { W = Wa; b = ba; nl = n; ncols = na; }
    else if (n < na + nb) { W = Wb; b = bb; nl = n - na; ncols = nb; }
    else { W = Wc; b = bc; nl = n - na - nb; ncols = nc; }
    float v = W[(size_t)k * ncols + nl];
    ushort h = f32_to_bf16_rn(v);
    ushort l = f32_to_bf16_rn(v - bf16u_to_f32(h));
    Wt_hi[(size_t)n * K + k] = h;
    Wt_lo[(size_t)n * K + k] = l;
    if (k == 0) bias_cat[n] = b[nl];
}

// ---------- split-bf16 MFMA GEMM: C[M][S] = A[M][K] @ Wt^T + bias ----------
// BM=128 (4 waves x 32 rows, mt=2), BN=64, BK=32.
// Double-buffered LDS for B (one barrier per k-step) + register prefetch of next A/B.
#define BSTRIDE 40
__global__ __launch_bounds__(256) void gemm_mfma_split(
        const ushort* __restrict__ Ahi, const ushort* __restrict__ Alo,
        const ushort* __restrict__ Wth, const ushort* __restrict__ Wtl,
        const float* __restrict__ bias, float* __restrict__ C,
        int M, int K, int S) {
    __shared__ ushort Bs_hi[2][64 * BSTRIDE];
    __shared__ ushort Bs_lo[2][64 * BSTRIDE];
    const int bm = blockIdx.y * 128;
    const int bn = blockIdx.x * 64;
    const int tid = threadIdx.x;
    const int wave = tid >> 6;
    const int lane = tid & 63;
    const int m16 = lane & 15;
    const int quad = lane >> 4;

    f32x4 acc[2][4];
    #pragma unroll
    for (int i = 0; i < 2; ++i)
        #pragma unroll
        for (int j = 0; j < 4; ++j) acc[i][j] = (f32x4){0.f, 0.f, 0.f, 0.f};

    const int srow = tid >> 2;    // B staging row 0..63
    const int schk = tid & 3;     // 16B chunk in 32-elem row
    const size_t bgo = (size_t)(bn + srow) * K + schk * 8;
    const int bso = srow * BSTRIDE + schk * 8;

    // A row addresses (clamped)
    int arow[2];
    #pragma unroll
    for (int mt = 0; mt < 2; ++mt) {
        int row = bm + wave * 32 + mt * 16 + m16;
        arow[mt] = row < M ? row : M - 1;
    }

    // ---- prologue: load tile 0, stage B into buffer 0 ----
    bf16x8 ah[2], al[2];
    {
        bf16x8 bh = *(const bf16x8*)(Wth + bgo);
        bf16x8 bl = *(const bf16x8*)(Wtl + bgo);
        #pragma unroll
        for (int mt = 0; mt < 2; ++mt) {
            size_t go = (size_t)arow[mt] * K + quad * 8;
            ah[mt] = *(const bf16x8*)(Ahi + go);
            al[mt] = *(const bf16x8*)(Alo + go);
        }
        *(bf16x8*)&Bs_hi[0][bso] = bh;
        *(bf16x8*)&Bs_lo[0][bso] = bl;
    }
    __syncthreads();

    int cur = 0;
    for (int k0 = 0; k0 < K; k0 += 32) {
        const bool more = (k0 + 32) < K;
        bf16x8 nbh, nbl, nah[2], nal[2];
        if (more) {
            nbh = *(const bf16x8*)(Wth + bgo + k0 + 32);
            nbl = *(const bf16x8*)(Wtl + bgo + k0 + 32);
            #pragma unroll
            for (int mt = 0; mt < 2; ++mt) {
                size_t go = (size_t)arow[mt] * K + k0 + 32 + quad * 8;
                nah[mt] = *(const bf16x8*)(Ahi + go);
                nal[mt] = *(const bf16x8*)(Alo + go);
            }
        }
        // ---- MFMA on current LDS buffer + current A regs ----
        #pragma unroll
        for (int nt = 0; nt < 4; ++nt) {
            int boff = (nt * 16 + m16) * BSTRIDE + quad * 8;
            bf16x8 bh = *(const bf16x8*)&Bs_hi[cur][boff];
            bf16x8 bl = *(const bf16x8*)&Bs_lo[cur][boff];
            #pragma unroll
            for (int mt = 0; mt < 2; ++mt) {
                acc[mt][nt] = __builtin_amdgcn_mfma_f32_16x16x32_bf16(ah[mt], bh, acc[mt][nt], 0, 0, 0);
                acc[mt][nt] = __builtin_amdgcn_mfma_f32_16x16x32_bf16(ah[mt], bl, acc[mt][nt], 0, 0, 0);
                acc[mt][nt] = __builtin_amdgcn_mfma_f32_16x16x32_bf16(al[mt], bh, acc[mt][nt], 0, 0, 0);
            }
        }
        if (more) {
            // write next tile into the *other* buffer (no reader conflict), one barrier
            *(bf16x8*)&Bs_hi[cur ^ 1][bso] = nbh;
            *(bf16x8*)&Bs_lo[cur ^ 1][bso] = nbl;
            #pragma unroll
            for (int mt = 0; mt < 2; ++mt) { ah[mt] = nah[mt]; al[mt] = nal[mt]; }
        }
        __syncthreads();
        cur ^= 1;
    }

    // epilogue: C/D layout col=lane&15, row=quad*4+reg
    #pragma unroll
    for (int nt = 0; nt < 4; ++nt) {
        int col = bn + nt * 16 + m16;
        float bv = bias[col];
        #pragma unroll
        for (int mt = 0; mt < 2; ++mt) {
            #pragma unroll
            for (int r = 0; r < 4; ++r) {
                int row = bm + wave * 32 + mt * 16 + quad * 4 + r;
                if (row < M) C[(size_t)row * S + col] = acc[mt][nt][r] + bv;
            }
        }
    }
}

// ---------- CSR build ----------
__global__ void zero_u32(unsigned int* __restrict__ p, int n) {
    int i = blockIdx.x * blockDim.x + threadIdx.x;
    if (i < n) p[i] = 0u;
}

__global__ void hist_dst(const int* __restrict__ dst, unsigned int* __restrict__ deg, int E) {
    int e = blockIdx.x * blockDim.x + threadIdx.x;
    if (e < E) atomicAdd(&deg[dst[e]], 1u);
}

__global__ void scan_deg(const unsigned int* __restrict__ deg,
                         unsigned int* __restrict__ row_ptr,
                         unsigned int* __restrict__ cursor, int n) {
    __shared__ unsigned int sums[1024];
    const int t = threadIdx.x;
    const int chunk = (n + 1023) / 1024;
    const int start = t * chunk;
    const int end = min(start + chunk, n);
    unsigned int s = 0;
    for (int i = start; i < end; ++i) s += deg[i];
    sums[t] = s;
    __syncthreads();
    for (int off = 1; off < 1024; off <<= 1) {
        unsigned int v = (t >= off) ? sums[t - off] : 0u;
        __syncthreads();
        sums[t] += v;
        __syncthreads();
    }
    unsigned int prefix = (t == 0) ? 0u : sums[t - 1];
    for (int i = start; i < end; ++i) {
        row_ptr[i] = prefix;
        cursor[i] = prefix;
        prefix += deg[i];
    }
    if (t == 1023) row_ptr[n] = sums[1023];
}

__global__ void scatter_edges(const int* __restrict__ src, const int* __restrict__ dst,
                              unsigned int* __restrict__ cursor,
                              int* __restrict__ csr_src, int E) {
    int e = blockIdx.x * blockDim.x + threadIdx.x;
    if (e < E) {
        unsigned int pos = atomicAdd(&cursor[dst[e]], 1u);
        csr_src[pos] = src[e];
    }
}

// ---------- fused GATv2 aggregate: one wave per node, float4 lanes, depth-4 prefetch ----------
// Lane i owns dims 4i..4i+3 (one head: 4 | D). Butterfly over D/4 lanes.
// OUT_MODE: 0 = fp32 out + bf16 hi/lo; 1 = bf16 hi/lo only; 2 = head-mean -> out[N,32].
template <int HD, int D, bool HAS_RES, bool DO_ELU, int OUT_MODE>
__global__ __launch_bounds__(256) void gat_node_aggregate(
        const float* __restrict__ feat, int FS,
        const float* __restrict__ attn,
        const unsigned int* __restrict__ row_ptr,
        const int* __restrict__ csr_src,
        const float* __restrict__ resid, int RS,
        float* __restrict__ outF, ushort* __restrict__ outH, ushort* __restrict__ outL) {
    constexpr int LANES = HD / 4;   // active lanes per node (64 or 48)
    constexpr int GSZ = D / 4;      // lanes per head group (16 or 8)
    __shared__ float red[4][(OUT_MODE == 2) ? HD : 1];

    const int wave = threadIdx.x >> 6;
    const int lane = threadIdx.x & 63;
    const int t = blockIdx.x * 4 + wave;
    const bool active = (lane < LANES);
    const int off = active ? 4 * lane : 0;   // inactive lanes alias dim 0 (valid addr)

    float4 fdv = make_float4(0.f, 0.f, 0.f, 0.f);
    float4 a6 = fdv, a4 = fdv;
    if (active) {
        fdv = *(const float4*)&feat[(size_t)t * FS + HD + off];
        float4 a = *(const float4*)&attn[off];
        a6 = make_float4(0.6f * a.x, 0.6f * a.y, 0.6f * a.z, 0.6f * a.w);
        a4 = make_float4(0.4f * a.x, 0.4f * a.y, 0.4f * a.z, 0.4f * a.w);
    }

    const int jj0 = (int)row_ptr[t], jj1 = (int)row_ptr[t + 1];
    const int last = jj1 - 1;

    float4 acc = make_float4(0.f, 0.f, 0.f, 0.f);
    float lh = 0.f, mh = -INFINITY;

    float4 b0 = acc, b1 = acc, b2 = acc, b3 = acc;
    if (jj0 < jj1) {   // wave-uniform; clamped prefetch of 4 gathers
        b0 = *(const float4*)&feat[(size_t)csr_src[jj0] * FS + off];
        b1 = *(const float4*)&feat[(size_t)csr_src[min(jj0 + 1, last)] * FS + off];
        b2 = *(const float4*)&feat[(size_t)csr_src[min(jj0 + 2, last)] * FS + off];
        b3 = *(const float4*)&feat[(size_t)csr_src[min(jj0 + 3, last)] * FS + off];
    }

    for (int j = jj0; j < jj1; ++j) {
        const float4 fsv = b0;
        b0 = b1; b1 = b2; b2 = b3;
        {   // always-issue clamped prefetch (tail loads are redundant cache hits)
            int jn = j + 4 < last ? j + 4 : last;
            b3 = *(const float4*)&feat[(size_t)csr_src[jn] * FS + off];
        }
        float x0 = fsv.x + fdv.x, x1 = fsv.y + fdv.y;
        float x2 = fsv.z + fdv.z, x3 = fsv.w + fdv.w;
        float p = x0 * a6.x + fabsf(x0) * a4.x;
        p += x1 * a6.y + fabsf(x1) * a4.y;
        p += x2 * a6.z + fabsf(x2) * a4.z;
        p += x3 * a6.w + fabsf(x3) * a4.w;
        #pragma unroll
        for (int o = 1; o < GSZ; o <<= 1)
            p += __shfl_xor(p, o, 64);
        float nm = fmaxf(mh, p);
        float sc = __expf(mh - nm);
        float w = __expf(p - nm);
        lh = lh * sc + w;
        acc.x = acc.x * sc + w * fsv.x;
        acc.y = acc.y * sc + w * fsv.y;
        acc.z = acc.z * sc + w * fsv.z;
        acc.w = acc.w * sc + w * fsv.w;
        mh = nm;
    }

    float inv = (lh > 0.f) ? 1.f / lh : 0.f;
    float4 vout = make_float4(acc.x * inv, acc.y * inv, acc.z * inv, acc.w * inv);
    if (HAS_RES && active) {
        float4 r = *(const float4*)&resid[(size_t)t * RS + off];
        vout.x += r.x; vout.y += r.y; vout.z += r.z; vout.w += r.w;
    }
    if (DO_ELU) {
        vout.x = vout.x > 0.f ? vout.x : expm1f(vout.x);
        vout.y = vout.y > 0.f ? vout.y : expm1f(vout.y);
        vout.z = vout.z > 0.f ? vout.z : expm1f(vout.z);
        vout.w = vout.w > 0.f ? vout.w : expm1f(vout.w);
    }

    if (OUT_MODE == 2) {
        if (active) *(float4*)&red[wave][off] = vout;
        __syncthreads();
        if (lane < 32) {
            float ssum = 0.f;
            #pragma unroll
            for (int h = 0; h < 6; ++h) ssum += red[wave][h * 32 + lane];
            outF[(size_t)t * 32 + lane] = ssum * (1.f / 6.f);
        }
    } else if (active) {
        ushort4 hv = make_ushort4(f32_to_bf16_rn(vout.x), f32_to_bf16_rn(vout.y),
                                  f32_to_bf16_rn(vout.z), f32_to_bf16_rn(vout.w));
        ushort4 lv = make_ushort4(f32_to_bf16_rn(vout.x - bf16u_to_f32(hv.x)),
                                  f32_to_bf16_rn(vout.y - bf16u_to_f32(hv.y)),
                                  f32_to_bf16_rn(vout.z - bf16u_to_f32(hv.z)),
                                  f32_to_bf16_rn(vout.w - bf16u_to_f32(hv.w)));
        *(ushort4*)&outH[(size_t)t * HD + off] = hv;
        *(ushort4*)&outL[(size_t)t * HD + off] = lv;
        if (OUT_MODE == 0) *(float4*)&outF[(size_t)t * HD + off] = vout;
    }
}

extern "C" void kernel_launch(void* const* d_in, const int* in_sizes, int n_in,
                              void* d_out, int out_size, void* d_ws, size_t ws_size,
                              hipStream_t stream) {
    const float* x   = (const float*)d_in[0];
    const int*   src = (const int*)d_in[1];
    const int*   dst = (const int*)d_in[2];
    const float* W0s = (const float*)d_in[3];
    const float* b0s = (const float*)d_in[4];
    const float* W0d = (const float*)d_in[5];
    const float* b0d = (const float*)d_in[6];
    const float* a0  = (const float*)d_in[7];
    const float* W1s = (const float*)d_in[8];
    const float* b1s = (const float*)d_in[9];
    const float* W1d = (const float*)d_in[10];
    const float* b1d = (const float*)d_in[11];
    const float* a1  = (const float*)d_in[12];
    const float* W2s = (const float*)d_in[13];
    const float* b2s = (const float*)d_in[14];
    const float* W2d = (const float*)d_in[15];
    const float* b2d = (const float*)d_in[16];
    const float* a2  = (const float*)d_in[17];
    const float* Wr2 = (const float*)d_in[18];
    const float* br2 = (const float*)d_in[19];

    // ---- workspace layout ----
    float* fsd = (float*)d_ws;                       // N*576 fp32 (max layer width)
    float* O0  = fsd + (size_t)NN * 576;             // N*256 (L0 out fp32 = L1 residual)
    ushort* Ah = (ushort*)(O0 + (size_t)NN * 256);   // N*256 bf16
    ushort* Al = Ah + (size_t)NN * 256;              // N*256
    ushort* Wt0h = Al + (size_t)NN * 256;            // 512*128
    ushort* Wt0l = Wt0h + 512 * 128;
    ushort* Wt1h = Wt0l + 512 * 128;                 // 512*256
    ushort* Wt1l = Wt1h + 512 * 256;
    ushort* Wt2h = Wt1l + 512 * 256;                 // 576*256
    ushort* Wt2l = Wt2h + 576 * 256;
    float* bias0 = (float*)(Wt2l + 576 * 256);       // 512
    float* bias1 = bias0 + 512;                      // 512
    float* bias2 = bias1 + 512;                      // 576
    unsigned int* row_ptr = (unsigned int*)(bias2 + 576);  // N+1
    unsigned int* cursor  = row_ptr + (NN + 1);
    unsigned int* deg     = cursor + NN;
    int* csr_src          = (int*)(deg + NN);        // E

    // ---- build CSR ----
    zero_u32<<<(NN + 255) / 256, 256, 0, stream>>>(deg, NN);
    hist_dst<<<(EE + 255) / 256, 256, 0, stream>>>(dst, deg, EE);
    scan_deg<<<1, 1024, 0, stream>>>(deg, row_ptr, cursor, NN);
    scatter_edges<<<(EE + 255) / 256, 256, 0, stream>>>(src, dst, cursor, csr_src, EE);

    // ---- prep all weights ----
    prep_w<<<(512 * 128 + 255) / 256, 256, 0, stream>>>(
        W0s, b0s, 256, W0d, b0d, 256, nullptr, nullptr, 0, 128, Wt0h, Wt0l, bias0);
    prep_w<<<(512 * 256 + 255) / 256, 256, 0, stream>>>(
        W1s, b1s, 256, W1d, b1d, 256, nullptr, nullptr, 0, 256, Wt1h, Wt1l, bias1);
    prep_w<<<(576 * 256 + 255) / 256, 256, 0, stream>>>(
        W2s, b2s, 192, W2d, b2d, 192, Wr2, br2, 192, 256, Wt2h, Wt2l, bias2);

    const int gy = (NN + 127) / 128;  // 157 (BM=128)
    const int nagg = NN / 4;          // 5000 blocks, 4 nodes (waves) each

    // ---- layer 0: x[N,128] -> fsd[N,512] -> O0 fp32 + Ah/Al bf16 ----
    split_f32<<<((NN * 128 / 4) + 255) / 256, 256, 0, stream>>>(x, Ah, Al, NN * 128 / 4);
    gemm_mfma_split<<<dim3(8, gy), 256, 0, stream>>>(Ah, Al, Wt0h, Wt0l, bias0, fsd,
                                                     NN, 128, 512);
    gat_node_aggregate<256, 64, false, true, 0><<<nagg, 256, 0, stream>>>(
        fsd, 512, a0, row_ptr, csr_src, nullptr, 0, O0, Ah, Al);

    // ---- layer 1: Ah/Al -> fsd[N,512] -> Ah/Al (identity residual O0) ----
    gemm_mfma_split<<<dim3(8, gy), 256, 0, stream>>>(Ah, Al, Wt1h, Wt1l, bias1, fsd,
                                                     NN, 256, 512);
    gat_node_aggregate<256, 64, true, true, 1><<<nagg, 256, 0, stream>>>(
        fsd, 512, a1, row_ptr, csr_src, O0, 256, nullptr, Ah, Al);

    // ---- layer 2: Ah/Al -> fsd[N,576] (fs|fd|res) -> d_out[N,32] ----
    gemm_mfma_split<<<dim3(9, gy), 256, 0, stream>>>(Ah, Al, Wt2h, Wt2l, bias2, fsd,
                                                     NN, 256, 576);
    gat_node_aggregate<192, 32, true, false, 2><<<nagg, 256, 0, stream>>>(
        fsd, 576, a2, row_ptr, csr_src, fsd + 384, 576, (float*)d_out, nullptr, nullptr);
}

// Round 8
// 417.570 us; speedup vs baseline: 1.1138x; 1.0749x over previous
//
#include <hip/hip_runtime.h>
#include <hip/hip_bf16.h>
#include <float.h>
#include <math.h>

// Problem constants (from reference)
#define NN 20000
#define EE 320000
#define IN_DIM 128
#define SLOPE_ 0.2f

typedef __attribute__((ext_vector_type(8))) short bf16x8;
typedef __attribute__((ext_vector_type(4))) float f32x4;
typedef unsigned short ushort;

// ---------- bf16 helpers ----------
__device__ inline ushort f32_to_bf16_rn(float f) {
    unsigned u = __float_as_uint(f);
    unsigned rounding = 0x7FFFu + ((u >> 16) & 1u);
    return (ushort)((u + rounding) >> 16);
}
__device__ inline float bf16u_to_f32(ushort h) {
    return __uint_as_float(((unsigned)h) << 16);
}

// ---------- split fp32 -> (hi, lo) bf16 (used only for input x) ----------
__global__ void split_f32(const float* __restrict__ A, ushort* __restrict__ hi,
                          ushort* __restrict__ lo, int n4) {
    int i = blockIdx.x * blockDim.x + threadIdx.x;
    if (i >= n4) return;
    float4 v = ((const float4*)A)[i];
    ushort h0 = f32_to_bf16_rn(v.x), h1 = f32_to_bf16_rn(v.y);
    ushort h2 = f32_to_bf16_rn(v.z), h3 = f32_to_bf16_rn(v.w);
    ushort l0 = f32_to_bf16_rn(v.x - bf16u_to_f32(h0));
    ushort l1 = f32_to_bf16_rn(v.y - bf16u_to_f32(h1));
    ushort l2 = f32_to_bf16_rn(v.z - bf16u_to_f32(h2));
    ushort l3 = f32_to_bf16_rn(v.w - bf16u_to_f32(h3));
    ((ushort4*)hi)[i] = make_ushort4(h0, h1, h2, h3);
    ((ushort4*)lo)[i] = make_ushort4(l0, l1, l2, l3);
}

// ---------- weight prep: concat + transpose + split, plus bias concat ----------
__global__ void prep_w(const float* __restrict__ Wa, const float* __restrict__ ba, int na,
                       const float* __restrict__ Wb, const float* __restrict__ bb, int nb,
                       const float* __restrict__ Wc, const float* __restrict__ bc, int nc,
                       int K, ushort* __restrict__ Wt_hi, ushort* __restrict__ Wt_lo,
                       float* __restrict__ bias_cat) {
    int idx = blockIdx.x * blockDim.x + threadIdx.x;
    int S = na + nb + nc;
    if (idx >= S * K) return;
    int n = idx / K;
    int k = idx - n * K;
    const float* W; const float* b; int nl; int ncols;
    if (n < na) { W = Wa; b = ba; nl = n; ncols = na; }
    else if (n < na + nb) { W = Wb; b = bb; nl = n - na; ncols = nb; }
    else { W = Wc; b = bc; nl = n - na - nb; ncols = nc; }
    float v = W[(size_t)k * ncols + nl];
    ushort h = f32_to_bf16_rn(v);
    ushort l = f32_to_bf16_rn(v - bf16u_to_f32(h));
    Wt_hi[(size_t)n * K + k] = h;
    Wt_lo[(size_t)n * K + k] = l;
    if (k == 0) bias_cat[n] = b[nl];
}

// ---------- split-bf16 MFMA GEMM with XCD-aware swizzle + split outputs ----------
// BM=128 (4 waves x 32 rows, mt=2), BN=64, BK=32, single-buffer LDS for B.
// 1D grid; xcd = bid&7; same-XCD consecutive blocks walk all bn of one bm
// so the A-tile is fetched once per XCD L2 (kills the 8x A re-fetch).
// Output columns routed to 3 dense buffers: [0,b1) -> F0, [b1,b2) -> F1, [b2,S) -> F2.
#define BSTRIDE 40
__global__ __launch_bounds__(256) void gemm_mfma_split(
        const ushort* __restrict__ Ahi, const ushort* __restrict__ Alo,
        const ushort* __restrict__ Wth, const ushort* __restrict__ Wtl,
        const float* __restrict__ bias,
        float* __restrict__ F0, float* __restrict__ F1, float* __restrict__ F2,
        int b1, int b2, int M, int K, int S, int gx, int gy) {
    __shared__ ushort Bs_hi[64 * BSTRIDE];
    __shared__ ushort Bs_lo[64 * BSTRIDE];

    const int bid = blockIdx.x;
    const int p = bid & 7;          // XCD slot
    const int q = bid >> 3;
    const int bn_i = q % gx;
    const int bm_i = (q / gx) * 8 + p;
    if (bm_i >= gy) return;
    const int bm = bm_i * 128;
    const int bn = bn_i * 64;

    const int tid = threadIdx.x;
    const int wave = tid >> 6;
    const int lane = tid & 63;
    const int m16 = lane & 15;
    const int quad = lane >> 4;

    f32x4 acc[2][4];
    #pragma unroll
    for (int i = 0; i < 2; ++i)
        #pragma unroll
        for (int j = 0; j < 4; ++j) acc[i][j] = (f32x4){0.f, 0.f, 0.f, 0.f};

    const int srow = tid >> 2;
    const int schk = tid & 3;

    for (int k0 = 0; k0 < K; k0 += 32) {
        {
            size_t goff = (size_t)(bn + srow) * K + k0 + schk * 8;
            bf16x8 vh = *(const bf16x8*)(Wth + goff);
            bf16x8 vl = *(const bf16x8*)(Wtl + goff);
            *(bf16x8*)&Bs_hi[srow * BSTRIDE + schk * 8] = vh;
            *(bf16x8*)&Bs_lo[srow * BSTRIDE + schk * 8] = vl;
        }
        bf16x8 ah[2], al[2];
        #pragma unroll
        for (int mt = 0; mt < 2; ++mt) {
            int row = bm + wave * 32 + mt * 16 + m16;
            row = row < M ? row : M - 1;
            size_t goff = (size_t)row * K + k0 + quad * 8;
            ah[mt] = *(const bf16x8*)(Ahi + goff);
            al[mt] = *(const bf16x8*)(Alo + goff);
        }
        __syncthreads();
        #pragma unroll
        for (int nt = 0; nt < 4; ++nt) {
            int boff = (nt * 16 + m16) * BSTRIDE + quad * 8;
            bf16x8 bh = *(const bf16x8*)&Bs_hi[boff];
            bf16x8 bl = *(const bf16x8*)&Bs_lo[boff];
            #pragma unroll
            for (int mt = 0; mt < 2; ++mt) {
                acc[mt][nt] = __builtin_amdgcn_mfma_f32_16x16x32_bf16(ah[mt], bh, acc[mt][nt], 0, 0, 0);
                acc[mt][nt] = __builtin_amdgcn_mfma_f32_16x16x32_bf16(ah[mt], bl, acc[mt][nt], 0, 0, 0);
                acc[mt][nt] = __builtin_amdgcn_mfma_f32_16x16x32_bf16(al[mt], bh, acc[mt][nt], 0, 0, 0);
            }
        }
        __syncthreads();
    }

    // epilogue: route 16-col tiles to the right output buffer (boundaries are x64)
    #pragma unroll
    for (int nt = 0; nt < 4; ++nt) {
        int col0 = bn + nt * 16;
        float* base; int cstride, cb;
        if (col0 >= b2)      { base = F2; cb = col0 - b2; cstride = S - b2; }
        else if (col0 >= b1) { base = F1; cb = col0 - b1; cstride = b2 - b1; }
        else                 { base = F0; cb = col0;      cstride = b1; }
        int col = cb + m16;
        float bv = bias[col0 + m16];
        #pragma unroll
        for (int mt = 0; mt < 2; ++mt) {
            #pragma unroll
            for (int r = 0; r < 4; ++r) {
                int row = bm + wave * 32 + mt * 16 + quad * 4 + r;
                if (row < M) base[(size_t)row * cstride + col] = acc[mt][nt][r] + bv;
            }
        }
    }
}

// ---------- CSR build ----------
__global__ void zero_u32(unsigned int* __restrict__ p, int n) {
    int i = blockIdx.x * blockDim.x + threadIdx.x;
    if (i < n) p[i] = 0u;
}

__global__ void hist_dst(const int* __restrict__ dst, unsigned int* __restrict__ deg, int E) {
    int e = blockIdx.x * blockDim.x + threadIdx.x;
    if (e < E) atomicAdd(&deg[dst[e]], 1u);
}

__global__ void scan_deg(const unsigned int* __restrict__ deg,
                         unsigned int* __restrict__ row_ptr,
                         unsigned int* __restrict__ cursor, int n) {
    __shared__ unsigned int sums[1024];
    const int t = threadIdx.x;
    const int chunk = (n + 1023) / 1024;
    const int start = t * chunk;
    const int end = min(start + chunk, n);
    unsigned int s = 0;
    for (int i = start; i < end; ++i) s += deg[i];
    sums[t] = s;
    __syncthreads();
    for (int off = 1; off < 1024; off <<= 1) {
        unsigned int v = (t >= off) ? sums[t - off] : 0u;
        __syncthreads();
        sums[t] += v;
        __syncthreads();
    }
    unsigned int prefix = (t == 0) ? 0u : sums[t - 1];
    for (int i = start; i < end; ++i) {
        row_ptr[i] = prefix;
        cursor[i] = prefix;
        prefix += deg[i];
    }
    if (t == 1023) row_ptr[n] = sums[1023];
}

__global__ void scatter_edges(const int* __restrict__ src, const int* __restrict__ dst,
                              unsigned int* __restrict__ cursor,
                              int* __restrict__ csr_src, int E) {
    int e = blockIdx.x * blockDim.x + threadIdx.x;
    if (e < E) {
        unsigned int pos = atomicAdd(&cursor[dst[e]], 1u);
        csr_src[pos] = src[e];
    }
}

// ---------- fused GATv2 aggregate: one wave per node, float4 lanes, depth-4 prefetch ----------
// fs/fd in separate dense buffers (stride HD). Lane i owns dims 4i..4i+3.
// OUT_MODE: 0 = fp32 out + bf16 hi/lo; 1 = bf16 hi/lo only; 2 = head-mean -> out[N,32].
template <int HD, int D, bool HAS_RES, bool DO_ELU, int OUT_MODE>
__global__ __launch_bounds__(256) void gat_node_aggregate(
        const float* __restrict__ fsb, const float* __restrict__ fdb,
        const float* __restrict__ attn,
        const unsigned int* __restrict__ row_ptr,
        const int* __restrict__ csr_src,
        const float* __restrict__ resid, int RS,
        float* __restrict__ outF, ushort* __restrict__ outH, ushort* __restrict__ outL) {
    constexpr int LANES = HD / 4;   // active lanes per node (64 or 48)
    constexpr int GSZ = D / 4;      // lanes per head group (16 or 8)
    __shared__ float red[4][(OUT_MODE == 2) ? HD : 1];

    const int wave = threadIdx.x >> 6;
    const int lane = threadIdx.x & 63;
    const int t = blockIdx.x * 4 + wave;
    const bool active = (lane < LANES);
    const int off = active ? 4 * lane : 0;   // inactive lanes alias dim 0 (valid addr)

    float4 fdv = make_float4(0.f, 0.f, 0.f, 0.f);
    float4 a6 = fdv, a4 = fdv;
    if (active) {
        fdv = *(const float4*)&fdb[(size_t)t * HD + off];
        float4 a = *(const float4*)&attn[off];
        a6 = make_float4(0.6f * a.x, 0.6f * a.y, 0.6f * a.z, 0.6f * a.w);
        a4 = make_float4(0.4f * a.x, 0.4f * a.y, 0.4f * a.z, 0.4f * a.w);
    }

    const int jj0 = (int)row_ptr[t], jj1 = (int)row_ptr[t + 1];
    const int last = jj1 - 1;

    float4 acc = make_float4(0.f, 0.f, 0.f, 0.f);
    float lh = 0.f, mh = -INFINITY;

    float4 b0 = acc, b1 = acc, b2 = acc, b3 = acc;
    if (jj0 < jj1) {   // wave-uniform; clamped prefetch of 4 gathers
        b0 = *(const float4*)&fsb[(size_t)csr_src[jj0] * HD + off];
        b1 = *(const float4*)&fsb[(size_t)csr_src[min(jj0 + 1, last)] * HD + off];
        b2 = *(const float4*)&fsb[(size_t)csr_src[min(jj0 + 2, last)] * HD + off];
        b3 = *(const float4*)&fsb[(size_t)csr_src[min(jj0 + 3, last)] * HD + off];
    }

    for (int j = jj0; j < jj1; ++j) {
        const float4 fsv = b0;
        b0 = b1; b1 = b2; b2 = b3;
        {   // always-issue clamped prefetch (tail loads are redundant cache hits)
            int jn = j + 4 < last ? j + 4 : last;
            b3 = *(const float4*)&fsb[(size_t)csr_src[jn] * HD + off];
        }
        float x0 = fsv.x + fdv.x, x1 = fsv.y + fdv.y;
        float x2 = fsv.z + fdv.z, x3 = fsv.w + fdv.w;
        float p = x0 * a6.x + fabsf(x0) * a4.x;
        p += x1 * a6.y + fabsf(x1) * a4.y;
        p += x2 * a6.z + fabsf(x2) * a4.z;
        p += x3 * a6.w + fabsf(x3) * a4.w;
        #pragma unroll
        for (int o = 1; o < GSZ; o <<= 1)
            p += __shfl_xor(p, o, 64);
        float nm = fmaxf(mh, p);
        float sc = __expf(mh - nm);
        float w = __expf(p - nm);
        lh = lh * sc + w;
        acc.x = acc.x * sc + w * fsv.x;
        acc.y = acc.y * sc + w * fsv.y;
        acc.z = acc.z * sc + w * fsv.z;
        acc.w = acc.w * sc + w * fsv.w;
        mh = nm;
    }

    float inv = (lh > 0.f) ? 1.f / lh : 0.f;
    float4 vout = make_float4(acc.x * inv, acc.y * inv, acc.z * inv, acc.w * inv);
    if (HAS_RES && active) {
        float4 r = *(const float4*)&resid[(size_t)t * RS + off];
        vout.x += r.x; vout.y += r.y; vout.z += r.z; vout.w += r.w;
    }
    if (DO_ELU) {
        vout.x = vout.x > 0.f ? vout.x : expm1f(vout.x);
        vout.y = vout.y > 0.f ? vout.y : expm1f(vout.y);
        vout.z = vout.z > 0.f ? vout.z : expm1f(vout.z);
        vout.w = vout.w > 0.f ? vout.w : expm1f(vout.w);
    }

    if (OUT_MODE == 2) {
        if (active) *(float4*)&red[wave][off] = vout;
        __syncthreads();
        if (lane < 32) {
            float ssum = 0.f;
            #pragma unroll
            for (int h = 0; h < 6; ++h) ssum += red[wave][h * 32 + lane];
            outF[(size_t)t * 32 + lane] = ssum * (1.f / 6.f);
        }
    } else if (active) {
        ushort4 hv = make_ushort4(f32_to_bf16_rn(vout.x), f32_to_bf16_rn(vout.y),
                                  f32_to_bf16_rn(vout.z), f32_to_bf16_rn(vout.w));
        ushort4 lv = make_ushort4(f32_to_bf16_rn(vout.x - bf16u_to_f32(hv.x)),
                                  f32_to_bf16_rn(vout.y - bf16u_to_f32(hv.y)),
                                  f32_to_bf16_rn(vout.z - bf16u_to_f32(hv.z)),
                                  f32_to_bf16_rn(vout.w - bf16u_to_f32(hv.w)));
        *(ushort4*)&outH[(size_t)t * HD + off] = hv;
        *(ushort4*)&outL[(size_t)t * HD + off] = lv;
        if (OUT_MODE == 0) *(float4*)&outF[(size_t)t * HD + off] = vout;
    }
}

extern "C" void kernel_launch(void* const* d_in, const int* in_sizes, int n_in,
                              void* d_out, int out_size, void* d_ws, size_t ws_size,
                              hipStream_t stream) {
    const float* x   = (const float*)d_in[0];
    const int*   src = (const int*)d_in[1];
    const int*   dst = (const int*)d_in[2];
    const float* W0s = (const float*)d_in[3];
    const float* b0s = (const float*)d_in[4];
    const float* W0d = (const float*)d_in[5];
    const float* b0d = (const float*)d_in[6];
    const float* a0  = (const float*)d_in[7];
    const float* W1s = (const float*)d_in[8];
    const float* b1s = (const float*)d_in[9];
    const float* W1d = (const float*)d_in[10];
    const float* b1d = (const float*)d_in[11];
    const float* a1  = (const float*)d_in[12];
    const float* W2s = (const float*)d_in[13];
    const float* b2s = (const float*)d_in[14];
    const float* W2d = (const float*)d_in[15];
    const float* b2d = (const float*)d_in[16];
    const float* a2  = (const float*)d_in[17];
    const float* Wr2 = (const float*)d_in[18];
    const float* br2 = (const float*)d_in[19];

    // ---- workspace layout (dense split buffers; O0 doubles as L2 residual Fr) ----
    float* Fs = (float*)d_ws;                        // N*256 (fs, dense)
    float* Fd = Fs + (size_t)NN * 256;               // N*256 (fd, dense)
    float* O0 = Fd + (size_t)NN * 256;               // N*256 (L1 residual fp32; later L2 res proj N*192)
    ushort* Ah = (ushort*)(O0 + (size_t)NN * 256);   // N*256 bf16
    ushort* Al = Ah + (size_t)NN * 256;              // N*256
    ushort* Wt0h = Al + (size_t)NN * 256;            // 512*128
    ushort* Wt0l = Wt0h + 512 * 128;
    ushort* Wt1h = Wt0l + 512 * 128;                 // 512*256
    ushort* Wt1l = Wt1h + 512 * 256;
    ushort* Wt2h = Wt1l + 512 * 256;                 // 576*256
    ushort* Wt2l = Wt2h + 576 * 256;
    float* bias0 = (float*)(Wt2l + 576 * 256);       // 512
    float* bias1 = bias0 + 512;                      // 512
    float* bias2 = bias1 + 512;                      // 576
    unsigned int* row_ptr = (unsigned int*)(bias2 + 576);  // N+1
    unsigned int* cursor  = row_ptr + (NN + 1);
    unsigned int* deg     = cursor + NN;
    int* csr_src          = (int*)(deg + NN);        // E

    // ---- build CSR ----
    zero_u32<<<(NN + 255) / 256, 256, 0, stream>>>(deg, NN);
    hist_dst<<<(EE + 255) / 256, 256, 0, stream>>>(dst, deg, EE);
    scan_deg<<<1, 1024, 0, stream>>>(deg, row_ptr, cursor, NN);
    scatter_edges<<<(EE + 255) / 256, 256, 0, stream>>>(src, dst, cursor, csr_src, EE);

    // ---- prep all weights ----
    prep_w<<<(512 * 128 + 255) / 256, 256, 0, stream>>>(
        W0s, b0s, 256, W0d, b0d, 256, nullptr, nullptr, 0, 128, Wt0h, Wt0l, bias0);
    prep_w<<<(512 * 256 + 255) / 256, 256, 0, stream>>>(
        W1s, b1s, 256, W1d, b1d, 256, nullptr, nullptr, 0, 256, Wt1h, Wt1l, bias1);
    prep_w<<<(576 * 256 + 255) / 256, 256, 0, stream>>>(
        W2s, b2s, 192, W2d, b2d, 192, Wr2, br2, 192, 256, Wt2h, Wt2l, bias2);

    const int gy = (NN + 127) / 128;           // 157 bm tiles
    const int gy8 = ((gy + 7) / 8) * 8;        // 160 (rounded for swizzle)
    const int nagg = NN / 4;                   // 5000 blocks, 4 nodes (waves) each

    // ---- layer 0: x[N,128] -> Fs/Fd[N,256] -> O0 fp32 + Ah/Al bf16 ----
    split_f32<<<((NN * 128 / 4) + 255) / 256, 256, 0, stream>>>(x, Ah, Al, NN * 128 / 4);
    gemm_mfma_split<<<gy8 * 8, 256, 0, stream>>>(Ah, Al, Wt0h, Wt0l, bias0,
                                                 Fs, Fd, O0, 256, 512, NN, 128, 512, 8, gy);
    gat_node_aggregate<256, 64, false, true, 0><<<nagg, 256, 0, stream>>>(
        Fs, Fd, a0, row_ptr, csr_src, nullptr, 0, O0, Ah, Al);

    // ---- layer 1: Ah/Al -> Fs/Fd[N,256] -> Ah/Al (identity residual O0) ----
    gemm_mfma_split<<<gy8 * 8, 256, 0, stream>>>(Ah, Al, Wt1h, Wt1l, bias1,
                                                 Fs, Fd, O0, 256, 512, NN, 256, 512, 8, gy);
    gat_node_aggregate<256, 64, true, true, 1><<<nagg, 256, 0, stream>>>(
        Fs, Fd, a1, row_ptr, csr_src, O0, 256, nullptr, Ah, Al);

    // ---- layer 2: Ah/Al -> Fs/Fd[N,192] + Fr(=O0)[N,192] -> d_out[N,32] ----
    gemm_mfma_split<<<gy8 * 9, 256, 0, stream>>>(Ah, Al, Wt2h, Wt2l, bias2,
                                                 Fs, Fd, O0, 192, 384, NN, 256, 576, 9, gy);
    gat_node_aggregate<192, 32, true, false, 2><<<nagg, 256, 0, stream>>>(
        Fs, Fd, a2, row_ptr, csr_src, O0, 192, (float*)d_out, nullptr, nullptr);
}

// Round 9
// 392.980 us; speedup vs baseline: 1.1835x; 1.0626x over previous
//
#include <hip/hip_runtime.h>
#include <hip/hip_bf16.h>
#include <float.h>
#include <math.h>

// Problem constants (from reference)
#define NN 20000
#define EE 320000
#define IN_DIM 128
#define SLOPE_ 0.2f

typedef __attribute__((ext_vector_type(8))) short bf16x8;
typedef __attribute__((ext_vector_type(4))) float f32x4;
typedef _Float16 f16;
typedef __attribute__((ext_vector_type(4))) _Float16 f16x4;
typedef unsigned short ushort;

// ---------- bf16 helpers ----------
__device__ inline ushort f32_to_bf16_rn(float f) {
    unsigned u = __float_as_uint(f);
    unsigned rounding = 0x7FFFu + ((u >> 16) & 1u);
    return (ushort)((u + rounding) >> 16);
}
__device__ inline float bf16u_to_f32(ushort h) {
    return __uint_as_float(((unsigned)h) << 16);
}

// ---------- weight prep element: concat + transpose + split ----------
__device__ inline void prep_elem(const float* __restrict__ Wa, const float* __restrict__ ba, int na,
                                 const float* __restrict__ Wb, const float* __restrict__ bb, int nb,
                                 const float* __restrict__ Wc, const float* __restrict__ bc, int nc,
                                 int K, ushort* __restrict__ Wth, ushort* __restrict__ Wtl,
                                 float* __restrict__ bias_cat, int idx) {
    int n = idx / K;
    int k = idx - n * K;
    const float* W; const float* b; int nl; int ncols;
    if (n < na) { W = Wa; b = ba; nl = n; ncols = na; }
    else if (n < na + nb) { W = Wb; b = bb; nl = n - na; ncols = nb; }
    else { W = Wc; b = bc; nl = n - na - nb; ncols = nc; }
    float v = W[(size_t)k * ncols + nl];
    ushort h = f32_to_bf16_rn(v);
    ushort l = f32_to_bf16_rn(v - bf16u_to_f32(h));
    Wth[(size_t)n * K + k] = h;
    Wtl[(size_t)n * K + k] = l;
    if (k == 0) bias_cat[n] = b[nl];
}

// ---------- one launch: all 3 weight preps + x split ----------
#define SEG0 (512 * 128)
#define SEG1 (512 * 256)
#define SEG2 (576 * 256)
#define SEG3 (NN * IN_DIM / 4)
__global__ void prep_all(const float* __restrict__ W0s, const float* __restrict__ b0s,
                         const float* __restrict__ W0d, const float* __restrict__ b0d,
                         const float* __restrict__ W1s, const float* __restrict__ b1s,
                         const float* __restrict__ W1d, const float* __restrict__ b1d,
                         const float* __restrict__ W2s, const float* __restrict__ b2s,
                         const float* __restrict__ W2d, const float* __restrict__ b2d,
                         const float* __restrict__ Wr2, const float* __restrict__ br2,
                         const float* __restrict__ x,
                         ushort* __restrict__ Wt0h, ushort* __restrict__ Wt0l, float* __restrict__ bias0,
                         ushort* __restrict__ Wt1h, ushort* __restrict__ Wt1l, float* __restrict__ bias1,
                         ushort* __restrict__ Wt2h, ushort* __restrict__ Wt2l, float* __restrict__ bias2,
                         ushort* __restrict__ Ah, ushort* __restrict__ Al) {
    int idx = blockIdx.x * 256 + threadIdx.x;
    if (idx < SEG0) {
        prep_elem(W0s, b0s, 256, W0d, b0d, 256, nullptr, nullptr, 0, 128, Wt0h, Wt0l, bias0, idx);
    } else if ((idx -= SEG0) < SEG1) {
        prep_elem(W1s, b1s, 256, W1d, b1d, 256, nullptr, nullptr, 0, 256, Wt1h, Wt1l, bias1, idx);
    } else if ((idx -= SEG1) < SEG2) {
        prep_elem(W2s, b2s, 192, W2d, b2d, 192, Wr2, br2, 192, 256, Wt2h, Wt2l, bias2, idx);
    } else if ((idx -= SEG2) < SEG3) {
        float4 v = ((const float4*)x)[idx];
        ushort h0 = f32_to_bf16_rn(v.x), h1 = f32_to_bf16_rn(v.y);
        ushort h2 = f32_to_bf16_rn(v.z), h3 = f32_to_bf16_rn(v.w);
        ushort l0 = f32_to_bf16_rn(v.x - bf16u_to_f32(h0));
        ushort l1 = f32_to_bf16_rn(v.y - bf16u_to_f32(h1));
        ushort l2 = f32_to_bf16_rn(v.z - bf16u_to_f32(h2));
        ushort l3 = f32_to_bf16_rn(v.w - bf16u_to_f32(h3));
        ((ushort4*)Ah)[idx] = make_ushort4(h0, h1, h2, h3);
        ((ushort4*)Al)[idx] = make_ushort4(l0, l1, l2, l3);
    }
}

// ---------- split-bf16 MFMA GEMM, XCD swizzle, fp16 feature outputs ----------
// BM=128 (4 waves x 32 rows), BN=64, BK=32. Cols [0,b1)->FsH(f16), [b1,b2)->FdH(f16), [b2,S)->Fr(f32).
#define BSTRIDE 40
__global__ __launch_bounds__(256) void gemm_mfma_split(
        const ushort* __restrict__ Ahi, const ushort* __restrict__ Alo,
        const ushort* __restrict__ Wth, const ushort* __restrict__ Wtl,
        const float* __restrict__ bias,
        f16* __restrict__ F0, f16* __restrict__ F1, float* __restrict__ F2,
        int b1, int b2, int M, int K, int S, int gx, int gy) {
    __shared__ ushort Bs_hi[64 * BSTRIDE];
    __shared__ ushort Bs_lo[64 * BSTRIDE];

    const int bid = blockIdx.x;
    const int p = bid & 7;          // XCD slot
    const int q = bid >> 3;
    const int bn_i = q % gx;
    const int bm_i = (q / gx) * 8 + p;
    if (bm_i >= gy) return;
    const int bm = bm_i * 128;
    const int bn = bn_i * 64;

    const int tid = threadIdx.x;
    const int wave = tid >> 6;
    const int lane = tid & 63;
    const int m16 = lane & 15;
    const int quad = lane >> 4;

    f32x4 acc[2][4];
    #pragma unroll
    for (int i = 0; i < 2; ++i)
        #pragma unroll
        for (int j = 0; j < 4; ++j) acc[i][j] = (f32x4){0.f, 0.f, 0.f, 0.f};

    const int srow = tid >> 2;
    const int schk = tid & 3;

    for (int k0 = 0; k0 < K; k0 += 32) {
        {
            size_t goff = (size_t)(bn + srow) * K + k0 + schk * 8;
            bf16x8 vh = *(const bf16x8*)(Wth + goff);
            bf16x8 vl = *(const bf16x8*)(Wtl + goff);
            *(bf16x8*)&Bs_hi[srow * BSTRIDE + schk * 8] = vh;
            *(bf16x8*)&Bs_lo[srow * BSTRIDE + schk * 8] = vl;
        }
        bf16x8 ah[2], al[2];
        #pragma unroll
        for (int mt = 0; mt < 2; ++mt) {
            int row = bm + wave * 32 + mt * 16 + m16;
            row = row < M ? row : M - 1;
            size_t goff = (size_t)row * K + k0 + quad * 8;
            ah[mt] = *(const bf16x8*)(Ahi + goff);
            al[mt] = *(const bf16x8*)(Alo + goff);
        }
        __syncthreads();
        #pragma unroll
        for (int nt = 0; nt < 4; ++nt) {
            int boff = (nt * 16 + m16) * BSTRIDE + quad * 8;
            bf16x8 bh = *(const bf16x8*)&Bs_hi[boff];
            bf16x8 bl = *(const bf16x8*)&Bs_lo[boff];
            #pragma unroll
            for (int mt = 0; mt < 2; ++mt) {
                acc[mt][nt] = __builtin_amdgcn_mfma_f32_16x16x32_bf16(ah[mt], bh, acc[mt][nt], 0, 0, 0);
                acc[mt][nt] = __builtin_amdgcn_mfma_f32_16x16x32_bf16(ah[mt], bl, acc[mt][nt], 0, 0, 0);
                acc[mt][nt] = __builtin_amdgcn_mfma_f32_16x16x32_bf16(al[mt], bh, acc[mt][nt], 0, 0, 0);
            }
        }
        __syncthreads();
    }

    // epilogue: route 16-col tiles (boundaries are x64, so no tile straddles)
    #pragma unroll
    for (int nt = 0; nt < 4; ++nt) {
        int col0 = bn + nt * 16;
        float bv = bias[col0 + m16];
        if (col0 < b1) {
            int col = col0 + m16;
            #pragma unroll
            for (int mt = 0; mt < 2; ++mt)
                #pragma unroll
                for (int r = 0; r < 4; ++r) {
                    int row = bm + wave * 32 + mt * 16 + quad * 4 + r;
                    if (row < M) F0[(size_t)row * b1 + col] = (f16)(acc[mt][nt][r] + bv);
                }
        } else if (col0 < b2) {
            int col = col0 - b1 + m16;
            int cs = b2 - b1;
            #pragma unroll
            for (int mt = 0; mt < 2; ++mt)
                #pragma unroll
                for (int r = 0; r < 4; ++r) {
                    int row = bm + wave * 32 + mt * 16 + quad * 4 + r;
                    if (row < M) F1[(size_t)row * cs + col] = (f16)(acc[mt][nt][r] + bv);
                }
        } else {
            int col = col0 - b2 + m16;
            int cs = S - b2;
            #pragma unroll
            for (int mt = 0; mt < 2; ++mt)
                #pragma unroll
                for (int r = 0; r < 4; ++r) {
                    int row = bm + wave * 32 + mt * 16 + quad * 4 + r;
                    if (row < M) F2[(size_t)row * cs + col] = acc[mt][nt][r] + bv;
                }
        }
    }
}

// ---------- CSR build ----------
__global__ void zero_u32(unsigned int* __restrict__ p, int n) {
    int i = blockIdx.x * blockDim.x + threadIdx.x;
    if (i < n) p[i] = 0u;
}

__global__ void hist_dst(const int* __restrict__ dst, unsigned int* __restrict__ deg, int E) {
    int e = blockIdx.x * blockDim.x + threadIdx.x;
    if (e < E) atomicAdd(&deg[dst[e]], 1u);
}

__global__ void scan_deg(const unsigned int* __restrict__ deg,
                         unsigned int* __restrict__ row_ptr,
                         unsigned int* __restrict__ cursor, int n) {
    __shared__ unsigned int sums[1024];
    const int t = threadIdx.x;
    const int chunk = (n + 1023) / 1024;
    const int start = t * chunk;
    const int end = min(start + chunk, n);
    unsigned int s = 0;
    for (int i = start; i < end; ++i) s += deg[i];
    sums[t] = s;
    __syncthreads();
    for (int off = 1; off < 1024; off <<= 1) {
        unsigned int v = (t >= off) ? sums[t - off] : 0u;
        __syncthreads();
        sums[t] += v;
        __syncthreads();
    }
    unsigned int prefix = (t == 0) ? 0u : sums[t - 1];
    for (int i = start; i < end; ++i) {
        row_ptr[i] = prefix;
        cursor[i] = prefix;
        prefix += deg[i];
    }
    if (t == 1023) row_ptr[n] = sums[1023];
}

__global__ void scatter_edges(const int* __restrict__ src, const int* __restrict__ dst,
                              unsigned int* __restrict__ cursor,
                              int* __restrict__ csr_src, int E) {
    int e = blockIdx.x * blockDim.x + threadIdx.x;
    if (e < E) {
        unsigned int pos = atomicAdd(&cursor[dst[e]], 1u);
        csr_src[pos] = src[e];
    }
}

// ---------- fused GATv2 aggregate: wave/node, float4 lanes, depth-4 prefetch, fp16 gather ----------
// OUT_MODE: 0 = fp32 out + bf16 hi/lo; 1 = bf16 hi/lo only; 2 = head-mean -> out[N,32].
template <int HD, int D, bool HAS_RES, bool DO_ELU, int OUT_MODE>
__global__ __launch_bounds__(256) void gat_node_aggregate(
        const f16* __restrict__ fsb, const f16* __restrict__ fdb,
        const float* __restrict__ attn,
        const unsigned int* __restrict__ row_ptr,
        const int* __restrict__ csr_src,
        const float* __restrict__ resid, int RS,
        float* __restrict__ outF, ushort* __restrict__ outH, ushort* __restrict__ outL) {
    constexpr int LANES = HD / 4;   // active lanes per node (64 or 48)
    constexpr int GSZ = D / 4;      // lanes per head group (16 or 8)
    __shared__ float red[4][(OUT_MODE == 2) ? HD : 1];

    const int wave = threadIdx.x >> 6;
    const int lane = threadIdx.x & 63;
    const int t = blockIdx.x * 4 + wave;
    const bool active = (lane < LANES);
    const int off = active ? 4 * lane : 0;   // inactive lanes alias dim 0 (valid addr)

    float4 fdv = make_float4(0.f, 0.f, 0.f, 0.f);
    float4 a6 = fdv, a4 = fdv;
    if (active) {
        f16x4 dv = *(const f16x4*)&fdb[(size_t)t * HD + off];
        fdv = make_float4((float)dv.x, (float)dv.y, (float)dv.z, (float)dv.w);
        float4 a = *(const float4*)&attn[off];
        a6 = make_float4(0.6f * a.x, 0.6f * a.y, 0.6f * a.z, 0.6f * a.w);
        a4 = make_float4(0.4f * a.x, 0.4f * a.y, 0.4f * a.z, 0.4f * a.w);
    }

    const int jj0 = (int)row_ptr[t], jj1 = (int)row_ptr[t + 1];
    const int last = jj1 - 1;

    float4 acc = make_float4(0.f, 0.f, 0.f, 0.f);
    float lh = 0.f, mh = -INFINITY;

    f16x4 b0 = (f16x4){0, 0, 0, 0}, b1 = b0, b2 = b0, b3 = b0;
    if (jj0 < jj1) {   // wave-uniform; clamped prefetch of 4 gathers
        b0 = *(const f16x4*)&fsb[(size_t)csr_src[jj0] * HD + off];
        b1 = *(const f16x4*)&fsb[(size_t)csr_src[min(jj0 + 1, last)] * HD + off];
        b2 = *(const f16x4*)&fsb[(size_t)csr_src[min(jj0 + 2, last)] * HD + off];
        b3 = *(const f16x4*)&fsb[(size_t)csr_src[min(jj0 + 3, last)] * HD + off];
    }

    for (int j = jj0; j < jj1; ++j) {
        const f16x4 cur = b0;
        b0 = b1; b1 = b2; b2 = b3;
        {   // always-issue clamped prefetch (tail loads are redundant cache hits)
            int jn = j + 4 < last ? j + 4 : last;
            b3 = *(const f16x4*)&fsb[(size_t)csr_src[jn] * HD + off];
        }
        float4 fsv = make_float4((float)cur.x, (float)cur.y, (float)cur.z, (float)cur.w);
        float x0 = fsv.x + fdv.x, x1 = fsv.y + fdv.y;
        float x2 = fsv.z + fdv.z, x3 = fsv.w + fdv.w;
        float p = x0 * a6.x + fabsf(x0) * a4.x;
        p += x1 * a6.y + fabsf(x1) * a4.y;
        p += x2 * a6.z + fabsf(x2) * a4.z;
        p += x3 * a6.w + fabsf(x3) * a4.w;
        #pragma unroll
        for (int o = 1; o < GSZ; o <<= 1)
            p += __shfl_xor(p, o, 64);
        float nm = fmaxf(mh, p);
        float sc = __expf(mh - nm);
        float w = __expf(p - nm);
        lh = lh * sc + w;
        acc.x = acc.x * sc + w * fsv.x;
        acc.y = acc.y * sc + w * fsv.y;
        acc.z = acc.z * sc + w * fsv.z;
        acc.w = acc.w * sc + w * fsv.w;
        mh = nm;
    }

    float inv = (lh > 0.f) ? 1.f / lh : 0.f;
    float4 vout = make_float4(acc.x * inv, acc.y * inv, acc.z * inv, acc.w * inv);
    if (HAS_RES && active) {
        float4 r = *(const float4*)&resid[(size_t)t * RS + off];
        vout.x += r.x; vout.y += r.y; vout.z += r.z; vout.w += r.w;
    }
    if (DO_ELU) {
        vout.x = vout.x > 0.f ? vout.x : expm1f(vout.x);
        vout.y = vout.y > 0.f ? vout.y : expm1f(vout.y);
        vout.z = vout.z > 0.f ? vout.z : expm1f(vout.z);
        vout.w = vout.w > 0.f ? vout.w : expm1f(vout.w);
    }

    if (OUT_MODE == 2) {
        if (active) *(float4*)&red[wave][off] = vout;
        __syncthreads();
        if (lane < 32) {
            float ssum = 0.f;
            #pragma unroll
            for (int h = 0; h < 6; ++h) ssum += red[wave][h * 32 + lane];
            outF[(size_t)t * 32 + lane] = ssum * (1.f / 6.f);
        }
    } else if (active) {
        ushort4 hv = make_ushort4(f32_to_bf16_rn(vout.x), f32_to_bf16_rn(vout.y),
                                  f32_to_bf16_rn(vout.z), f32_to_bf16_rn(vout.w));
        ushort4 lv = make_ushort4(f32_to_bf16_rn(vout.x - bf16u_to_f32(hv.x)),
                                  f32_to_bf16_rn(vout.y - bf16u_to_f32(hv.y)),
                                  f32_to_bf16_rn(vout.z - bf16u_to_f32(hv.z)),
                                  f32_to_bf16_rn(vout.w - bf16u_to_f32(hv.w)));
        *(ushort4*)&outH[(size_t)t * HD + off] = hv;
        *(ushort4*)&outL[(size_t)t * HD + off] = lv;
        if (OUT_MODE == 0) *(float4*)&outF[(size_t)t * HD + off] = vout;
    }
}

extern "C" void kernel_launch(void* const* d_in, const int* in_sizes, int n_in,
                              void* d_out, int out_size, void* d_ws, size_t ws_size,
                              hipStream_t stream) {
    const float* x   = (const float*)d_in[0];
    const int*   src = (const int*)d_in[1];
    const int*   dst = (const int*)d_in[2];
    const float* W0s = (const float*)d_in[3];
    const float* b0s = (const float*)d_in[4];
    const float* W0d = (const float*)d_in[5];
    const float* b0d = (const float*)d_in[6];
    const float* a0  = (const float*)d_in[7];
    const float* W1s = (const float*)d_in[8];
    const float* b1s = (const float*)d_in[9];
    const float* W1d = (const float*)d_in[10];
    const float* b1d = (const float*)d_in[11];
    const float* a1  = (const float*)d_in[12];
    const float* W2s = (const float*)d_in[13];
    const float* b2s = (const float*)d_in[14];
    const float* W2d = (const float*)d_in[15];
    const float* b2d = (const float*)d_in[16];
    const float* a2  = (const float*)d_in[17];
    const float* Wr2 = (const float*)d_in[18];
    const float* br2 = (const float*)d_in[19];

    // ---- workspace layout ----
    f16* FsH = (f16*)d_ws;                           // N*256 f16 (fs, dense gather target)
    f16* FdH = FsH + (size_t)NN * 256;               // N*256 f16 (fd)
    float* O0 = (float*)(FdH + (size_t)NN * 256);    // N*256 fp32 (L1 residual; later L2 Fr N*192)
    ushort* Ah = (ushort*)(O0 + (size_t)NN * 256);   // N*256 bf16
    ushort* Al = Ah + (size_t)NN * 256;              // N*256
    ushort* Wt0h = Al + (size_t)NN * 256;            // 512*128
    ushort* Wt0l = Wt0h + 512 * 128;
    ushort* Wt1h = Wt0l + 512 * 128;                 // 512*256
    ushort* Wt1l = Wt1h + 512 * 256;
    ushort* Wt2h = Wt1l + 512 * 256;                 // 576*256
    ushort* Wt2l = Wt2h + 576 * 256;
    float* bias0 = (float*)(Wt2l + 576 * 256);       // 512
    float* bias1 = bias0 + 512;                      // 512
    float* bias2 = bias1 + 512;                      // 576
    unsigned int* row_ptr = (unsigned int*)(bias2 + 576);  // N+1
    unsigned int* cursor  = row_ptr + (NN + 1);
    unsigned int* deg     = cursor + NN;
    int* csr_src          = (int*)(deg + NN);        // E

    // ---- build CSR ----
    zero_u32<<<(NN + 255) / 256, 256, 0, stream>>>(deg, NN);
    hist_dst<<<(EE + 255) / 256, 256, 0, stream>>>(dst, deg, EE);
    scan_deg<<<1, 1024, 0, stream>>>(deg, row_ptr, cursor, NN);
    scatter_edges<<<(EE + 255) / 256, 256, 0, stream>>>(src, dst, cursor, csr_src, EE);

    // ---- all weight prep + x split in ONE launch ----
    {
        int total = SEG0 + SEG1 + SEG2 + SEG3;
        prep_all<<<(total + 255) / 256, 256, 0, stream>>>(
            W0s, b0s, W0d, b0d, W1s, b1s, W1d, b1d, W2s, b2s, W2d, b2d, Wr2, br2, x,
            Wt0h, Wt0l, bias0, Wt1h, Wt1l, bias1, Wt2h, Wt2l, bias2, Ah, Al);
    }

    const int gy = (NN + 127) / 128;           // 157 bm tiles
    const int gy8 = ((gy + 7) / 8) * 8;        // 160 (rounded for swizzle)
    const int nagg = NN / 4;                   // 5000 blocks, 4 nodes (waves) each

    // ---- layer 0: x[N,128] -> FsH/FdH[N,256] f16 -> O0 fp32 + Ah/Al bf16 ----
    gemm_mfma_split<<<gy8 * 8, 256, 0, stream>>>(Ah, Al, Wt0h, Wt0l, bias0,
                                                 FsH, FdH, nullptr, 256, 512, NN, 128, 512, 8, gy);
    gat_node_aggregate<256, 64, false, true, 0><<<nagg, 256, 0, stream>>>(
        FsH, FdH, a0, row_ptr, csr_src, nullptr, 0, O0, Ah, Al);

    // ---- layer 1: Ah/Al -> FsH/FdH[N,256] -> Ah/Al (identity residual O0 fp32) ----
    gemm_mfma_split<<<gy8 * 8, 256, 0, stream>>>(Ah, Al, Wt1h, Wt1l, bias1,
                                                 FsH, FdH, nullptr, 256, 512, NN, 256, 512, 8, gy);
    gat_node_aggregate<256, 64, true, true, 1><<<nagg, 256, 0, stream>>>(
        FsH, FdH, a1, row_ptr, csr_src, O0, 256, nullptr, Ah, Al);

    // ---- layer 2: Ah/Al -> FsH/FdH[N,192] + Fr(=O0 fp32)[N,192] -> d_out[N,32] ----
    gemm_mfma_split<<<gy8 * 9, 256, 0, stream>>>(Ah, Al, Wt2h, Wt2l, bias2,
                                                 FsH, FdH, O0, 192, 384, NN, 256, 576, 9, gy);
    gat_node_aggregate<192, 32, true, false, 2><<<nagg, 256, 0, stream>>>(
        FsH, FdH, a2, row_ptr, csr_src, O0, 192, (float*)d_out, nullptr, nullptr);
}